// Round 4
// baseline (216.372 us; speedup 1.0000x reference)
//
#include <hip/hip_runtime.h>
#include <hip/hip_bf16.h>

typedef _Float16 f16x8 __attribute__((ext_vector_type(8)));
typedef _Float16 f16x4 __attribute__((ext_vector_type(4)));
typedef float f32x4 __attribute__((ext_vector_type(4)));

__device__ __forceinline__ void async_ld16(_Float16* lds, const _Float16* g) {
    __builtin_amdgcn_global_load_lds(
        (const __attribute__((address_space(1))) void*)g,
        (__attribute__((address_space(3))) void*)lds, 16, 0, 0);
}

// per-z C destinations (pointer + row stride in f32 elements)
struct CDesc {
    float *p0, *p1, *p2, *p3;
    int l0, l1, l2, l3;
};

// C = A[M,K] * B[N,K]^T  (k-contiguous fp16 -> fp32), 128x128 tile, 4 waves
// 2x2, each wave 64x64 via 4x4 of 16x16x32 MFMA. Double-buffered LDS.
// lda/ldb: row strides of A/B in elements (rows may be wider than K extent).
// Split-K: blockIdx.z handles k in [z*Ks, (z+1)*Ks), writes C dest z.
__global__ __launch_bounds__(256) void gemm_bt(
    const _Float16* __restrict__ A,
    const _Float16* __restrict__ B,
    int M, int N, int Ks, int lda, int ldb, CDesc cd)
{
    __shared__ _Float16 At[2][128 * 32];
    __shared__ _Float16 Bt[2][128 * 32];

    const int tid  = threadIdx.x;
    const int wave = tid >> 6;
    const int lane = tid & 63;

    int gx = gridDim.x, gy = gridDim.y;
    int bx = blockIdx.x, by = blockIdx.y;
    if (((gx & 7) == 0) && ((gy & 7) == 0)) {
        const int bid    = bx + gx * by;
        const int ntx    = gx >> 3;
        const int sid    = bid >> 6;
        const int within = bid & 63;
        const int sx = sid % ntx;
        const int sy = sid / ntx;
        bx = (sx << 3) + (within & 7);
        by = (sy << 3) + (within >> 3);
    }
    const int row0 = by * 128;
    const int col0 = bx * 128;

    const int wr = (wave >> 1) * 64;
    const int wc = (wave & 1) * 64;
    const int quad = lane >> 4;
    const int l16  = lane & 15;

    f32x4 acc[4][4] = {};

    // staging: wave w fills LDS row-chunks w and w+4 (16 rows x 64B each);
    // global_load_lds dest = wave-uniform base + lane*16.
    const int srow  = lane >> 2;
    const int skoff = (lane & 3) * 8;
    const size_t K64a = (size_t)64 * lda;
    const size_t K64b = (size_t)64 * ldb;

    const int z = blockIdx.z;
    const _Float16* Ab = A + (size_t)row0 * lda + (size_t)z * Ks;
    const _Float16* Bb = B + (size_t)col0 * ldb + (size_t)z * Ks;

    const _Float16* pa = Ab + (size_t)(wave * 16 + srow) * lda + skoff;
    const _Float16* pb = Bb + (size_t)(wave * 16 + srow) * ldb + skoff;

    async_ld16(At[0] + wave * 512,       pa);
    async_ld16(At[0] + (wave + 4) * 512, pa + K64a);
    async_ld16(Bt[0] + wave * 512,       pb);
    async_ld16(Bt[0] + (wave + 4) * 512, pb + K64b);
    __syncthreads();

    int cur = 0;
    for (int k0 = 0; k0 < Ks; k0 += 32) {
        const int nxt = cur ^ 1;
        if (k0 + 32 < Ks) {
            const _Float16* qa = pa + k0 + 32;
            const _Float16* qb = pb + k0 + 32;
            async_ld16(At[nxt] + wave * 512,       qa);
            async_ld16(At[nxt] + (wave + 4) * 512, qa + K64a);
            async_ld16(Bt[nxt] + wave * 512,       qb);
            async_ld16(Bt[nxt] + (wave + 4) * 512, qb + K64b);
        }

        f16x8 af[4], bf[4];
        #pragma unroll
        for (int r = 0; r < 4; ++r)
            af[r] = *(const f16x8*)&At[cur][(wr + r * 16 + l16) * 32 + quad * 8];
        #pragma unroll
        for (int c = 0; c < 4; ++c)
            bf[c] = *(const f16x8*)&Bt[cur][(wc + c * 16 + l16) * 32 + quad * 8];

        #pragma unroll
        for (int r = 0; r < 4; ++r)
            #pragma unroll
            for (int c = 0; c < 4; ++c)
                acc[r][c] = __builtin_amdgcn_mfma_f32_16x16x32_f16(af[r], bf[c], acc[r][c], 0, 0, 0);

        __syncthreads();
        cur = nxt;
    }

    float* Cb; int ldc;
    if      (z == 0) { Cb = cd.p0; ldc = cd.l0; }
    else if (z == 1) { Cb = cd.p1; ldc = cd.l1; }
    else if (z == 2) { Cb = cd.p2; ldc = cd.l2; }
    else             { Cb = cd.p3; ldc = cd.l3; }

    // C/D layout: col = lane&15, row = quad*4 + reg   [verified m89/m91]
    #pragma unroll
    for (int r = 0; r < 4; ++r) {
        const int growb = row0 + wr + r * 16 + quad * 4;
        #pragma unroll
        for (int c = 0; c < 4; ++c) {
            const int gcol = col0 + wc + c * 16 + l16;
            #pragma unroll
            for (int i = 0; i < 4; ++i)
                Cb[(size_t)(growb + i) * ldc + gcol] = acc[r][c][i];
        }
    }
}

// one block per row; reads S f32 row [4096], writes P fp16 IN PLACE over the
// first half of the row (all reads complete before first barrier -> safe).
__global__ __launch_bounds__(256) void softmax_rows(
    float* __restrict__ S, float scale)
{
    __shared__ float red[4];
    const int row = blockIdx.x;
    const int tid = threadIdx.x;
    const int wave = tid >> 6;
    const float4* Sr = (const float4*)(S + (size_t)row * 4096);

    float4 x[4];
    #pragma unroll
    for (int i = 0; i < 4; ++i) x[i] = Sr[tid + i * 256];

    float mx = -3.402823466e+38f;
    #pragma unroll
    for (int i = 0; i < 4; ++i)
        mx = fmaxf(mx, fmaxf(fmaxf(x[i].x, x[i].y), fmaxf(x[i].z, x[i].w)));
    #pragma unroll
    for (int off = 32; off > 0; off >>= 1) mx = fmaxf(mx, __shfl_down(mx, off));
    if ((tid & 63) == 0) red[wave] = mx;
    __syncthreads();
    mx = fmaxf(fmaxf(red[0], red[1]), fmaxf(red[2], red[3]));
    __syncthreads();

    float sum = 0.0f;
    #pragma unroll
    for (int i = 0; i < 4; ++i) {
        x[i].x = __expf(x[i].x - mx);
        x[i].y = __expf(x[i].y - mx);
        x[i].z = __expf(x[i].z - mx);
        x[i].w = __expf(x[i].w - mx);
        sum += x[i].x + x[i].y + x[i].z + x[i].w;
    }
    #pragma unroll
    for (int off = 32; off > 0; off >>= 1) sum += __shfl_down(sum, off);
    if ((tid & 63) == 0) red[wave] = sum;
    __syncthreads();
    sum = red[0] + red[1] + red[2] + red[3];

    const float inv = scale / sum;
    f16x4* Pr = (f16x4*)((_Float16*)S + (size_t)row * 8192);
    #pragma unroll
    for (int i = 0; i < 4; ++i) {
        f16x4 h;
        h.x = (_Float16)(x[i].x * inv);
        h.y = (_Float16)(x[i].y * inv);
        h.z = (_Float16)(x[i].z * inv);
        h.w = (_Float16)(x[i].w * inv);
        Pr[tid + i * 256] = h;
    }
}

// convert two fp32 arrays to fp16 in one launch
__global__ __launch_bounds__(256) void cvt2_f32_f16(
    const float4* __restrict__ a, f16x4* __restrict__ da, int n4a,
    const float4* __restrict__ b, f16x4* __restrict__ db, int n4b)
{
    int i = blockIdx.x * 256 + threadIdx.x;
    const int stride = gridDim.x * 256;
    const int tot = n4a + n4b;
    for (; i < tot; i += stride) {
        const float4* s = (i < n4a) ? (a + i) : (b + (i - n4a));
        f16x4* d = (i < n4a) ? (da + i) : (db + (i - n4a));
        float4 v = *s;
        f16x4 h;
        h.x = (_Float16)v.x; h.y = (_Float16)v.y;
        h.z = (_Float16)v.z; h.w = (_Float16)v.w;
        *d = h;
    }
}

// Vt[c][r] = (f16) V[r][c];  V is rows x cols
__global__ __launch_bounds__(256) void transpose_cvt(
    const float* __restrict__ V, _Float16* __restrict__ Vt, int rows, int cols)
{
    __shared__ float tile[32][33];
    const int c0 = blockIdx.x * 32;
    const int r0 = blockIdx.y * 32;
    const int tx = threadIdx.x & 31;
    const int ty = threadIdx.x >> 5;
    #pragma unroll
    for (int i = 0; i < 4; ++i)
        tile[ty * 4 + i][tx] = V[(size_t)(r0 + ty * 4 + i) * cols + c0 + tx];
    __syncthreads();
    #pragma unroll
    for (int i = 0; i < 4; ++i)
        Vt[(size_t)(c0 + ty * 4 + i) * rows + r0 + tx] = (_Float16)tile[tx][ty * 4 + i];
}

// out[r][0:1024] += sum of nparts partials (each ptr + row stride in f32)
__global__ __launch_bounds__(256) void reduce_add(
    float4* __restrict__ out,
    const float* __restrict__ p1, int ld1,
    const float* __restrict__ p2, int ld2,
    const float* __restrict__ p3, int ld3,
    int nparts, int rows)
{
    int i = blockIdx.x * 256 + threadIdx.x;
    const int stride = gridDim.x * 256;
    const int tot = rows * 256;            // 256 float4 per 1024-wide row
    for (; i < tot; i += stride) {
        const int r = i >> 8, c = i & 255;
        float4 v = out[i];
        float4 a = ((const float4*)(p1 + (size_t)r * ld1))[c];
        v.x += a.x; v.y += a.y; v.z += a.z; v.w += a.w;
        if (nparts > 1) {
            float4 b = ((const float4*)(p2 + (size_t)r * ld2))[c];
            v.x += b.x; v.y += b.y; v.z += b.z; v.w += b.w;
        }
        if (nparts > 2) {
            float4 d = ((const float4*)(p3 + (size_t)r * ld3))[c];
            v.x += d.x; v.y += d.y; v.z += d.z; v.w += d.w;
        }
        out[i] = v;
    }
}

extern "C" void kernel_launch(void* const* d_in, const int* in_sizes, int n_in,
                              void* d_out, int out_size, void* d_ws, size_t ws_size,
                              hipStream_t stream) {
    const float* Q = (const float*)d_in[0];
    const float* K = (const float*)d_in[1];
    const float* V = (const float*)d_in[2];
    float* out = (float*)d_out;

    const int n = 4096, m = 4096, d = 1024, vdim = 1024;
    const float scale = 0.03125f;  // 1024^-0.5

    char* w = (char*)d_ws;
    _Float16* Qh = (_Float16*)w;                        // 8 MB
    _Float16* Kh = (_Float16*)(w + (8u << 20));         // 8 MB
    _Float16* Vt = (_Float16*)(w + (16u << 20));        // 8 MB
    char* rest = w + (24u << 20);
    size_t avail = ws_size > (24u << 20) ? ws_size - (24u << 20) : 0;

    // chunk footprint: S = nc rows x 16 KB (f32 4096-wide; P fp16 overwrites
    // first half in place; split-K partials live in the dead second half).
    // sk=4 additionally needs one dense nc x 1024 f32 partial after S.
    int nc, sk;
    if      (avail >= (size_t)4096 * 16384)                        { nc = 4096; sk = 2; }
    else if (avail >= (size_t)2048 * 16384 + (size_t)2048 * 4096)  { nc = 2048; sk = 4; }
    else if (avail >= (size_t)1024 * 16384 + (size_t)1024 * 4096)  { nc = 1024; sk = 4; }
    else                                                           { nc = 512;  sk = 4; }

    float* S = (float*)rest;                      // nc x 4096 f32
    float* pd1 = S + 2048;                        // dead-space partial, ld 4096
    float* pd2 = S + 3072;                        // dead-space partial, ld 4096
    float* pde = S + (size_t)nc * 4096;           // dense extra partial, ld 1024

    cvt2_f32_f16<<<dim3(2048), dim3(256), 0, stream>>>(
        (const float4*)Q, (f16x4*)Qh, n * d / 4,
        (const float4*)K, (f16x4*)Kh, m * d / 4);
    transpose_cvt<<<dim3(vdim / 32, m / 32), dim3(256), 0, stream>>>(V, Vt, m, vdim);

    for (int r0 = 0; r0 < n; r0 += nc) {
        // S = Qc * Kh^T   [nc x m]
        CDesc cs; cs.p0 = S; cs.l0 = m;
        cs.p1 = cs.p2 = cs.p3 = S; cs.l1 = cs.l2 = cs.l3 = m;
        gemm_bt<<<dim3(m / 128, nc / 128, 1), dim3(256), 0, stream>>>(
            Qh + (size_t)r0 * d, Kh, nc, m, d, d, d, cs);

        softmax_rows<<<dim3(nc), dim3(256), 0, stream>>>(S, scale);

        // O = P * Vt^T, split-K over keys; z=0 -> out, z>=1 -> partials
        float* o0 = out + (size_t)r0 * vdim;
        CDesc co;
        co.p0 = o0;  co.l0 = vdim;
        co.p1 = pd1; co.l1 = 4096;
        co.p2 = pd2; co.l2 = 4096;
        co.p3 = pde; co.l3 = vdim;
        gemm_bt<<<dim3(vdim / 128, nc / 128, sk), dim3(256), 0, stream>>>(
            (const _Float16*)S, Vt, nc, vdim, m / sk, 2 * m, m, co);

        reduce_add<<<dim3(1024), dim3(256), 0, stream>>>(
            (float4*)o0, pd1, 4096, pd2, 4096, pde, vdim, sk - 1, nc);
    }
}

// Round 5
// 215.620 us; speedup vs baseline: 1.0035x; 1.0035x over previous
//
#include <hip/hip_runtime.h>
#include <hip/hip_bf16.h>

typedef _Float16 f16x8 __attribute__((ext_vector_type(8)));
typedef _Float16 f16x4 __attribute__((ext_vector_type(4)));
typedef float f32x4 __attribute__((ext_vector_type(4)));

__device__ __forceinline__ void async_ld16(_Float16* lds, const _Float16* g) {
    __builtin_amdgcn_global_load_lds(
        (const __attribute__((address_space(1))) void*)g,
        (__attribute__((address_space(3))) void*)lds, 16, 0, 0);
}

// per-z C destinations (pointer + row stride in f32 elements)
struct CDesc {
    float *p0, *p1, *p2, *p3;
    int l0, l1, l2, l3;
};

// C = A[M,K] * B[N,K]^T  (k-contiguous fp16 -> fp32), 128x128 tile, 4 waves
// 2x2, each wave 64x64 via 4x4 of 16x16x32 MFMA. Double-buffered LDS.
// XCD-aware swizzle: dispatcher round-robins bids across the 8 XCDs, so
// bid&7 = XCD. Per XCD, sweep one 128-row A-band across all columns
// (A-slab ~256KB stays L2-resident; B streams through, re-served by L3).
// C stores are nontemporal so the 64MB f32 output doesn't evict B from L2.
__global__ __launch_bounds__(256) void gemm_bt(
    const _Float16* __restrict__ A,
    const _Float16* __restrict__ B,
    int M, int N, int Ks, int lda, int ldb, CDesc cd)
{
    __shared__ _Float16 At[2][128 * 32];
    __shared__ _Float16 Bt[2][128 * 32];

    const int tid  = threadIdx.x;
    const int wave = tid >> 6;
    const int lane = tid & 63;

    const int gx = gridDim.x, gy = gridDim.y;
    int bx = blockIdx.x, by = blockIdx.y;
    if ((gy & 7) == 0) {
        const int bid = bx + gx * by;
        const int x = bid & 7;           // XCD id (bid%8 round-robin)
        const int j = bid >> 3;
        bx = j % gx;
        by = x + 8 * (j / gx);
    }
    const int row0 = by * 128;
    const int col0 = bx * 128;

    const int wr = (wave >> 1) * 64;
    const int wc = (wave & 1) * 64;
    const int quad = lane >> 4;
    const int l16  = lane & 15;

    f32x4 acc[4][4] = {};

    // staging: wave w fills LDS row-chunks w and w+4 (16 rows x 64B each);
    // global_load_lds dest = wave-uniform base + lane*16.
    const int srow  = lane >> 2;
    const int skoff = (lane & 3) * 8;
    const size_t K64a = (size_t)64 * lda;
    const size_t K64b = (size_t)64 * ldb;

    const int z = blockIdx.z;
    const _Float16* Ab = A + (size_t)row0 * lda + (size_t)z * Ks;
    const _Float16* Bb = B + (size_t)col0 * ldb + (size_t)z * Ks;

    const _Float16* pa = Ab + (size_t)(wave * 16 + srow) * lda + skoff;
    const _Float16* pb = Bb + (size_t)(wave * 16 + srow) * ldb + skoff;

    async_ld16(At[0] + wave * 512,       pa);
    async_ld16(At[0] + (wave + 4) * 512, pa + K64a);
    async_ld16(Bt[0] + wave * 512,       pb);
    async_ld16(Bt[0] + (wave + 4) * 512, pb + K64b);
    __syncthreads();

    int cur = 0;
    for (int k0 = 0; k0 < Ks; k0 += 32) {
        const int nxt = cur ^ 1;
        if (k0 + 32 < Ks) {
            const _Float16* qa = pa + k0 + 32;
            const _Float16* qb = pb + k0 + 32;
            async_ld16(At[nxt] + wave * 512,       qa);
            async_ld16(At[nxt] + (wave + 4) * 512, qa + K64a);
            async_ld16(Bt[nxt] + wave * 512,       qb);
            async_ld16(Bt[nxt] + (wave + 4) * 512, qb + K64b);
        }

        f16x8 af[4], bf[4];
        #pragma unroll
        for (int r = 0; r < 4; ++r)
            af[r] = *(const f16x8*)&At[cur][(wr + r * 16 + l16) * 32 + quad * 8];
        #pragma unroll
        for (int c = 0; c < 4; ++c)
            bf[c] = *(const f16x8*)&Bt[cur][(wc + c * 16 + l16) * 32 + quad * 8];

        #pragma unroll
        for (int r = 0; r < 4; ++r)
            #pragma unroll
            for (int c = 0; c < 4; ++c)
                acc[r][c] = __builtin_amdgcn_mfma_f32_16x16x32_f16(af[r], bf[c], acc[r][c], 0, 0, 0);

        __syncthreads();
        cur = nxt;
    }

    float* Cb; int ldc;
    if      (z == 0) { Cb = cd.p0; ldc = cd.l0; }
    else if (z == 1) { Cb = cd.p1; ldc = cd.l1; }
    else if (z == 2) { Cb = cd.p2; ldc = cd.l2; }
    else             { Cb = cd.p3; ldc = cd.l3; }

    // C/D layout: col = lane&15, row = quad*4 + reg   [verified m89/m91]
    #pragma unroll
    for (int r = 0; r < 4; ++r) {
        const int growb = row0 + wr + r * 16 + quad * 4;
        #pragma unroll
        for (int c = 0; c < 4; ++c) {
            const int gcol = col0 + wc + c * 16 + l16;
            #pragma unroll
            for (int i = 0; i < 4; ++i)
                __builtin_nontemporal_store(
                    acc[r][c][i], &Cb[(size_t)(growb + i) * ldc + gcol]);
        }
    }
}

// one block per row; reads S f32 row [4096], writes P fp16 IN PLACE over the
// first half of the row (all reads complete before first barrier -> safe).
__global__ __launch_bounds__(256) void softmax_rows(
    float* __restrict__ S, float scale)
{
    __shared__ float red[4];
    const int row = blockIdx.x;
    const int tid = threadIdx.x;
    const int wave = tid >> 6;
    const float4* Sr = (const float4*)(S + (size_t)row * 4096);

    float4 x[4];
    #pragma unroll
    for (int i = 0; i < 4; ++i) x[i] = Sr[tid + i * 256];

    float mx = -3.402823466e+38f;
    #pragma unroll
    for (int i = 0; i < 4; ++i)
        mx = fmaxf(mx, fmaxf(fmaxf(x[i].x, x[i].y), fmaxf(x[i].z, x[i].w)));
    #pragma unroll
    for (int off = 32; off > 0; off >>= 1) mx = fmaxf(mx, __shfl_down(mx, off));
    if ((tid & 63) == 0) red[wave] = mx;
    __syncthreads();
    mx = fmaxf(fmaxf(red[0], red[1]), fmaxf(red[2], red[3]));
    __syncthreads();

    float sum = 0.0f;
    #pragma unroll
    for (int i = 0; i < 4; ++i) {
        x[i].x = __expf(x[i].x - mx);
        x[i].y = __expf(x[i].y - mx);
        x[i].z = __expf(x[i].z - mx);
        x[i].w = __expf(x[i].w - mx);
        sum += x[i].x + x[i].y + x[i].z + x[i].w;
    }
    #pragma unroll
    for (int off = 32; off > 0; off >>= 1) sum += __shfl_down(sum, off);
    if ((tid & 63) == 0) red[wave] = sum;
    __syncthreads();
    sum = red[0] + red[1] + red[2] + red[3];

    const float inv = scale / sum;
    f16x4* Pr = (f16x4*)((_Float16*)S + (size_t)row * 8192);
    #pragma unroll
    for (int i = 0; i < 4; ++i) {
        f16x4 h;
        h.x = (_Float16)(x[i].x * inv);
        h.y = (_Float16)(x[i].y * inv);
        h.z = (_Float16)(x[i].z * inv);
        h.w = (_Float16)(x[i].w * inv);
        Pr[tid + i * 256] = h;
    }
}

// convert two fp32 arrays to fp16 in one launch
__global__ __launch_bounds__(256) void cvt2_f32_f16(
    const float4* __restrict__ a, f16x4* __restrict__ da, int n4a,
    const float4* __restrict__ b, f16x4* __restrict__ db, int n4b)
{
    int i = blockIdx.x * 256 + threadIdx.x;
    const int stride = gridDim.x * 256;
    const int tot = n4a + n4b;
    for (; i < tot; i += stride) {
        const float4* s = (i < n4a) ? (a + i) : (b + (i - n4a));
        f16x4* d = (i < n4a) ? (da + i) : (db + (i - n4a));
        float4 v = *s;
        f16x4 h;
        h.x = (_Float16)v.x; h.y = (_Float16)v.y;
        h.z = (_Float16)v.z; h.w = (_Float16)v.w;
        *d = h;
    }
}

// Vt[c][r] = (f16) V[r][c];  V is rows x cols
__global__ __launch_bounds__(256) void transpose_cvt(
    const float* __restrict__ V, _Float16* __restrict__ Vt, int rows, int cols)
{
    __shared__ float tile[32][33];
    const int c0 = blockIdx.x * 32;
    const int r0 = blockIdx.y * 32;
    const int tx = threadIdx.x & 31;
    const int ty = threadIdx.x >> 5;
    #pragma unroll
    for (int i = 0; i < 4; ++i)
        tile[ty * 4 + i][tx] = V[(size_t)(r0 + ty * 4 + i) * cols + c0 + tx];
    __syncthreads();
    #pragma unroll
    for (int i = 0; i < 4; ++i)
        Vt[(size_t)(c0 + ty * 4 + i) * rows + r0 + tx] = (_Float16)tile[tx][ty * 4 + i];
}

// out[r][0:1024] += sum of nparts partials (each ptr + row stride in f32)
__global__ __launch_bounds__(256) void reduce_add(
    float4* __restrict__ out,
    const float* __restrict__ p1, int ld1,
    const float* __restrict__ p2, int ld2,
    const float* __restrict__ p3, int ld3,
    int nparts, int rows)
{
    int i = blockIdx.x * 256 + threadIdx.x;
    const int stride = gridDim.x * 256;
    const int tot = rows * 256;            // 256 float4 per 1024-wide row
    for (; i < tot; i += stride) {
        const int r = i >> 8, c = i & 255;
        float4 v = out[i];
        float4 a = ((const float4*)(p1 + (size_t)r * ld1))[c];
        v.x += a.x; v.y += a.y; v.z += a.z; v.w += a.w;
        if (nparts > 1) {
            float4 b = ((const float4*)(p2 + (size_t)r * ld2))[c];
            v.x += b.x; v.y += b.y; v.z += b.z; v.w += b.w;
        }
        if (nparts > 2) {
            float4 d = ((const float4*)(p3 + (size_t)r * ld3))[c];
            v.x += d.x; v.y += d.y; v.z += d.z; v.w += d.w;
        }
        out[i] = v;
    }
}

extern "C" void kernel_launch(void* const* d_in, const int* in_sizes, int n_in,
                              void* d_out, int out_size, void* d_ws, size_t ws_size,
                              hipStream_t stream) {
    const float* Q = (const float*)d_in[0];
    const float* K = (const float*)d_in[1];
    const float* V = (const float*)d_in[2];
    float* out = (float*)d_out;

    const int n = 4096, m = 4096, d = 1024, vdim = 1024;
    const float scale = 0.03125f;  // 1024^-0.5

    char* w = (char*)d_ws;
    _Float16* Qh = (_Float16*)w;                        // 8 MB
    _Float16* Kh = (_Float16*)(w + (8u << 20));         // 8 MB
    _Float16* Vt = (_Float16*)(w + (16u << 20));        // 8 MB
    char* rest = w + (24u << 20);
    size_t avail = ws_size > (24u << 20) ? ws_size - (24u << 20) : 0;

    // chunk footprint: S = nc rows x 16 KB (f32 4096-wide; P fp16 overwrites
    // first half in place; split-K partials live in the dead second half).
    int nc, sk;
    if      (avail >= (size_t)4096 * 16384)                        { nc = 4096; sk = 2; }
    else if (avail >= (size_t)2048 * 16384 + (size_t)2048 * 4096)  { nc = 2048; sk = 4; }
    else if (avail >= (size_t)1024 * 16384 + (size_t)1024 * 4096)  { nc = 1024; sk = 4; }
    else                                                           { nc = 512;  sk = 4; }

    float* S = (float*)rest;                      // nc x 4096 f32
    float* pd1 = S + 2048;                        // dead-space partial, ld 4096
    float* pd2 = S + 3072;                        // dead-space partial, ld 4096
    float* pde = S + (size_t)nc * 4096;           // dense extra partial, ld 1024

    cvt2_f32_f16<<<dim3(2048), dim3(256), 0, stream>>>(
        (const float4*)Q, (f16x4*)Qh, n * d / 4,
        (const float4*)K, (f16x4*)Kh, m * d / 4);
    transpose_cvt<<<dim3(vdim / 32, m / 32), dim3(256), 0, stream>>>(V, Vt, m, vdim);

    for (int r0 = 0; r0 < n; r0 += nc) {
        // S = Qc * Kh^T   [nc x m]
        CDesc cs; cs.p0 = S; cs.l0 = m;
        cs.p1 = cs.p2 = cs.p3 = S; cs.l1 = cs.l2 = cs.l3 = m;
        gemm_bt<<<dim3(m / 128, nc / 128, 1), dim3(256), 0, stream>>>(
            Qh + (size_t)r0 * d, Kh, nc, m, d, d, d, cs);

        softmax_rows<<<dim3(nc), dim3(256), 0, stream>>>(S, scale);

        // O = P * Vt^T, split-K over keys; z=0 -> out, z>=1 -> partials
        float* o0 = out + (size_t)r0 * vdim;
        CDesc co;
        co.p0 = o0;  co.l0 = vdim;
        co.p1 = pd1; co.l1 = 4096;
        co.p2 = pd2; co.l2 = 4096;
        co.p3 = pde; co.l3 = vdim;
        gemm_bt<<<dim3(vdim / 128, nc / 128, sk), dim3(256), 0, stream>>>(
            (const _Float16*)S, Vt, nc, vdim, m / sk, 2 * m, m, co);

        reduce_add<<<dim3(1024), dim3(256), 0, stream>>>(
            (float4*)o0, pd1, 4096, pd2, 4096, pde, vdim, sk - 1, nc);
    }
}